// Round 1
// baseline (104.938 us; speedup 1.0000x reference)
//
#include <hip/hip_runtime.h>
#include <math.h>

// Regular (3,6) QC-LDPC, rate 1/2 (constants from reference).
#define B_      128
#define N_      24576
#define NPAIR_  2048     // component PAIRS: thread owns components 2p and 2p+1
#define ITERS_  10
#define CLIP_   20.0f
#define NBLOCKS_ ((B_ * NPAIR_) / 256)   // 1024 WGs == exactly-resident at 4 WG/CU

// Structure proof (unchanged): edge_to_cn = e/6, edge_to_vn = e%N. Component k:
// CNs {k, k+4096, k+8192}, VNs {6k..6k+5}, 18 edges, fully independent.
// NEW: one thread decodes components {2p, 2p+1} -> 12 contiguous VNs ->
// float4 I/O, 2x independent dep-chains per lane, grid 1024 = all-resident.

__device__ __forceinline__ float fmed3(float a, float b, float c) {
    return __builtin_amdgcn_fmed3f(a, b, c);   // guaranteed v_med3_f32
}
__device__ __forceinline__ float clipf(float x)   { return fmed3(x, -CLIP_, CLIP_); }
__device__ __forceinline__ float clamp0c(float x) { return fmed3(x, 0.0f, CLIP_); }
__device__ __forceinline__ float fmin3(float a, float b, float c) {
    return fminf(fminf(a, b), c);              // v_min3_f32
}
// Force wave-uniform value into an SGPR (weights would squat in VGPRs).
__device__ __forceinline__ float rfl(float x) {
    return __uint_as_float(__builtin_amdgcn_readfirstlane(__float_as_uint(x)));
}

// (256,4): 128-VGPR cap. State: llr 12 + c2v 36 + sum 12 + acc 4 = 64 persistent
// + ~25 transient + addr ~= 95-115 live -> fits, no spill, scheduler has slack.
// Iteration loop ROLLED (body ~3.5KB, I$-resident); weights re-read per lap via
// the scalar/constant-cache path instead of 30 pinned SGPR-array slots.
__global__ __launch_bounds__(256, 4) void ldpc_fused_kernel(
    const float* __restrict__ llr_in,     // [B, N]
    const float* __restrict__ cn_weight,  // [ITERS]
    const float* __restrict__ ch_weight,  // [ITERS]
    const float* __restrict__ cn_bias,    // [ITERS]
    float* __restrict__ out,              // [0]=loss (finalize), [1..]=dec [B,N]
    double* __restrict__ partials)        // d_ws: one slot per block, no atomics
{
    const int gid = blockIdx.x * 256 + threadIdx.x;
    const int b = gid >> 11;              // / NPAIR_
    const int p = gid & (NPAIR_ - 1);

    // 12 contiguous channel LLRs (16B-aligned: byte offset = 48p + 98304b)
    const float4* p4 = (const float4*)(llr_in + b * N_ + 12 * p);
    float4 q0 = p4[0], q1 = p4[1], q2 = p4[2];
    float llr[2][6] = {
        { q0.x, q0.y, q0.z, q0.w, q1.x, q1.y },
        { q1.z, q1.w, q2.x, q2.y, q2.z, q2.w }
    };

    float c2v[2][3][6];
    float sum[2][6];
#pragma unroll
    for (int g = 0; g < 2; ++g)
#pragma unroll
        for (int i = 0; i < 6; ++i) {
            sum[g][i] = 0.f;
            c2v[g][0][i] = 0.f; c2v[g][1][i] = 0.f; c2v[g][2][i] = 0.f;
        }

    // Per-component loss accumulators (kept separate: preserves per-component
    // f32 accumulation order of the verified kernel; also 2 independent chains)
    float accMax[2]  = { 0.f, 0.f };
    float prodLog[2] = { 1.f, 1.f };   // 60 terms in (1,2] each -> <= 2^60, safe

#pragma unroll 1   // keep rolled: full unroll would be ~35KB straight-line code
    for (int it = 0; it < ITERS_; ++it) {
        // uniform per-iteration weights; scalar-cache hits after first lap
        const float    cw    = rfl(ch_weight[it]);
        const float    w     = rfl(cn_weight[it]);
        const float    cnwa  = fabsf(w);
        const unsigned cnws  = __float_as_uint(w) & 0x80000000u;
        const float    nbias = -rfl(cn_bias[it]);

#pragma unroll
        for (int g = 0; g < 2; ++g) {
            // VN totals (shared by the 3 CNs of this component)
            float u6[6];
#pragma unroll
            for (int i = 0; i < 6; ++i) u6[i] = fmaf(llr[g][i], cw, sum[g][i]);

#pragma unroll
            for (int cn = 0; cn < 3; ++cn) {
                // v2c = clip(u - c2v); sign bits tracked via float bitcasts
                float t[6];
                unsigned par = cnws;        // fold cn_weight sign into parity
#pragma unroll
                for (int j = 0; j < 6; ++j) {
                    t[j] = clipf(u6[j] - c2v[g][cn][j]);
                    par ^= __float_as_uint(t[j]);   // only bit31 meaningful
                }
                // Two-min via sorted-triple merge (abs as VOP3 modifiers).
                // Exact incl. ties: dup-min => m2 == m1 -> select is bit-exact
                // vs reference m1/m2/cnt form.
                float minA = fmin3(fabsf(t[0]), fabsf(t[1]), fabsf(t[2]));
                float medA = fmed3(fabsf(t[0]), fabsf(t[1]), fabsf(t[2]));
                float minB = fmin3(fabsf(t[3]), fabsf(t[4]), fabsf(t[5]));
                float medB = fmed3(fabsf(t[3]), fabsf(t[4]), fabsf(t[5]));
                float m1 = fminf(minA, minB);
                float m2 = fmin3(fmaxf(minA, minB), medA, medB);
                // Only two possible output magnitudes per CN:
                float M1p = clamp0c(fmaf(m1, cnwa, nbias));
                float M2p = clamp0c(fmaf(m2, cnwa, nbias));
#pragma unroll
                for (int j = 0; j < 6; ++j) {
                    float ext = (fabsf(t[j]) == m1) ? M2p : M1p;
                    unsigned sx = par ^ __float_as_uint(t[j]); // sign of others
                    // v_bfi_b32: bit31 from sx, rest from ext
                    c2v[g][cn][j] = __uint_as_float((sx & 0x80000000u)
                                                    | __float_as_uint(ext));
                }
            }

            // marginals + loss (add order per component matches verified kernel)
#pragma unroll
            for (int i = 0; i < 6; ++i) {
                sum[g][i] = (c2v[g][0][i] + c2v[g][1][i]) + c2v[g][2][i];
                float dec = llr[g][i] + sum[g][i];
                // softplus(-dec) = max(-dec,0) + log(1+exp(-|dec|));
                // log terms accumulated as a product, ONE log per component.
                accMax[g]  += fmaxf(-dec, 0.f);
                prodLog[g] *= 1.f + __expf(-fabsf(dec));
            }
        }
    }

    // final dec: 12 contiguous floats -> 3 x dwordx4 (unaligned-mode OK,
    // same precedent as the verified float2-at-4mod8 stores)
    float d[12];
#pragma unroll
    for (int g = 0; g < 2; ++g)
#pragma unroll
        for (int i = 0; i < 6; ++i) d[6 * g + i] = llr[g][i] + sum[g][i];

    float4* outd = (float4*)(out + 1 + b * N_ + 12 * p);
    outd[0] = make_float4(d[0], d[1], d[2],  d[3]);
    outd[1] = make_float4(d[4], d[5], d[6],  d[7]);
    outd[2] = make_float4(d[8], d[9], d[10], d[11]);

    // loss: wave64 shuffle -> LDS -> ONE PLAIN STORE per block (no atomics;
    // same-address RMWs previously pinned the kernel ~105us).
    float local_loss = (accMax[0] + __logf(prodLog[0]))
                     + (accMax[1] + __logf(prodLog[1]));
#pragma unroll
    for (int off = 32; off > 0; off >>= 1)
        local_loss += __shfl_down(local_loss, off);
    __shared__ float wsum[4];
    const int lane = threadIdx.x & 63;
    const int wid  = threadIdx.x >> 6;
    if (lane == 0) wsum[wid] = local_loss;
    __syncthreads();
    if (threadIdx.x == 0) {
        double t = ((double)wsum[0] + (double)wsum[1])
                 + ((double)wsum[2] + (double)wsum[3]);
        partials[blockIdx.x] = t;      // distinct address per block
    }
}

__global__ __launch_bounds__(256) void ldpc_finalize_kernel(
    const double* __restrict__ partials,  // [NBLOCKS_]
    float* __restrict__ out)
{
    double s = 0.0;
#pragma unroll
    for (int i = 0; i < NBLOCKS_ / 256; ++i)           // 4 loads/thread
        s += partials[threadIdx.x + 256 * i];
#pragma unroll
    for (int off = 32; off > 0; off >>= 1)
        s += __shfl_down(s, off);
    __shared__ double wsum[4];
    const int lane = threadIdx.x & 63;
    const int wid  = threadIdx.x >> 6;
    if (lane == 0) wsum[wid] = s;
    __syncthreads();
    if (threadIdx.x == 0) {
        double total = (wsum[0] + wsum[1]) + (wsum[2] + wsum[3]);
        out[0] = (float)(total * (1.0 / ((double)B_ * (double)N_)));
    }
}

extern "C" void kernel_launch(void* const* d_in, const int* in_sizes, int n_in,
                              void* d_out, int out_size, void* d_ws, size_t ws_size,
                              hipStream_t stream) {
    const float* llr_in    = (const float*)d_in[0];
    const float* cn_weight = (const float*)d_in[1];
    const float* ch_weight = (const float*)d_in[2];
    const float* cn_bias   = (const float*)d_in[3];
    // d_in[4]/d_in[5] (edge maps) unused: structure is closed-form (e%N, e/6).

    float*  out      = (float*)d_out;
    double* partials = (double*)d_ws;     // 1024 doubles = 8 KB, all overwritten

    ldpc_fused_kernel<<<NBLOCKS_, 256, 0, stream>>>(
        llr_in, cn_weight, ch_weight, cn_bias, out, partials);
    ldpc_finalize_kernel<<<1, 256, 0, stream>>>(partials, out);
}

// Round 2
// 102.632 us; speedup vs baseline: 1.0225x; 1.0225x over previous
//
#include <hip/hip_runtime.h>
#include <math.h>

// Regular (3,6) QC-LDPC, rate 1/2 (constants from reference).
#define B_     128
#define N_     24576
#define NCOMP_ 4096      // graph decomposes into 4096 independent components
#define ITERS_ 10
#define CLIP_  20.0f
#define NBLOCKS_ ((B_ * NCOMP_) / 256)   // 2048

// Structure proof: edge_to_cn = e/6, edge_to_vn = e%N. CN c owns edges [6c,6c+6).
// For c = k, k+4096, k+8192 those edges map to VNs {6k..6k+5} exactly.
// => component k: CNs {k, k+4096, k+8192}, VNs {6k..6k+5}, 18 edges; fully
// independent of all other components -> whole decode fits in one thread.
//
// R4 (this round): the 18 c2v floats/thread move to LDS ([row][tid] layout,
// conflict-free, compile-time row offsets). Persistent VGPR state drops to
// ~14 -> fits the 64-VGPR cap of (256,8) WITHOUT the spill that killed the
// historical (256,8) attempt. Grid 2048 WGs at 8/CU = every thread resident
// in ONE batch (round 0 ran 6-then-2 generations at (256,6)).

__device__ __forceinline__ float fmed3(float a, float b, float c) {
    return __builtin_amdgcn_fmed3f(a, b, c);   // v_med3_f32
}
__device__ __forceinline__ float clipf(float x)   { return fmed3(x, -CLIP_, CLIP_); }
__device__ __forceinline__ float clamp0c(float x) { return fmed3(x, 0.0f, CLIP_); }
__device__ __forceinline__ float fmin3(float a, float b, float c) {
    return fminf(fminf(a, b), c);              // v_min3_f32
}
// Force a wave-uniform value into an SGPR (weights: 40 scalars otherwise
// squatting in VGPRs for the whole kernel).
__device__ __forceinline__ float rfl(float x) {
    return __uint_as_float(__builtin_amdgcn_readfirstlane(__float_as_uint(x)));
}

__global__ __launch_bounds__(256, 8) void ldpc_fused_kernel(
    const float* __restrict__ llr_in,     // [B, N]
    const float* __restrict__ cn_weight,  // [ITERS]
    const float* __restrict__ ch_weight,  // [ITERS]
    const float* __restrict__ cn_bias,    // [ITERS]
    float* __restrict__ out,              // [0]=loss (finalize), [1..]=dec [B,N]
    double* __restrict__ partials)        // d_ws: one slot per block, no atomics
{
    // c2v state in LDS: row = cn*6+j, column = thread. Lane t -> byte t*4 ->
    // bank t%32: 2 lanes/bank (free). Row stride 1024B -> 16-bit offset imm.
    // Each thread touches ONLY its own column -> no barriers in the loop.
    __shared__ float c2v_lds[18][256];
    __shared__ float wsum[4];

    const int tid = threadIdx.x;
    const int gid = blockIdx.x * 256 + tid;
    const int b = gid >> 12;              // / NCOMP_
    const int k = gid & (NCOMP_ - 1);

    // Per-iteration weights -> SGPRs (uniform; statically indexed under the
    // full unroll, so the arrays never touch memory).
    float cwv[ITERS_], cnwa[ITERS_], nbias[ITERS_];
    unsigned cnws[ITERS_];
#pragma unroll
    for (int i = 0; i < ITERS_; ++i) {
        float w  = rfl(cn_weight[i]);
        cwv[i]   = rfl(ch_weight[i]);
        cnwa[i]  = fabsf(w);
        cnws[i]  = __float_as_uint(w) & 0x80000000u;
        nbias[i] = -rfl(cn_bias[i]);
    }

    // 6 contiguous channel LLRs for this component (8B-aligned: offset = 24k B)
    const float2* p2 = (const float2*)(llr_in + b * N_ + 6 * k);
    float2 t0 = p2[0], t1 = p2[1], t2 = p2[2];
    float llr[6] = {t0.x, t0.y, t1.x, t1.y, t2.x, t2.y};

#pragma unroll
    for (int r = 0; r < 18; ++r) c2v_lds[r][tid] = 0.f;

    float sum[6] = {0.f, 0.f, 0.f, 0.f, 0.f, 0.f};

    float accMax  = 0.f;   // sum of max(-dec,0) terms
    float prodLog = 1.f;   // prod of (1+exp(-|dec|)); 60 terms, each in (1,2]
                           // => product <= 2^60, no overflow; ONE log at end.

#pragma unroll
    for (int it = 0; it < ITERS_; ++it) {
        const float cw = cwv[it];

        // VN totals (shared by the 3 CNs of this component)
        float u6[6];
#pragma unroll
        for (int i = 0; i < 6; ++i) u6[i] = fmaf(llr[i], cw, sum[i]);

#pragma unroll
        for (int cn = 0; cn < 3; ++cn) {
            // v2c = clip(u - c2v_old); sign bits tracked via float bitcasts
            float t[6];
            unsigned par = cnws[it];       // fold cn_weight sign into parity
#pragma unroll
            for (int j = 0; j < 6; ++j) {
                t[j] = clipf(u6[j] - c2v_lds[cn * 6 + j][tid]);
                par ^= __float_as_uint(t[j]);   // only bit31 meaningful
            }
            // Two-min via sorted-triple merge (abs folded as VOP3 modifiers):
            //   m1 = min(minA, minB)
            //   m2 = min3(max(minA,minB), medA, medB)
            // Exact incl. ties: dup-min => m2 == m1, so the (a==m1)?m2:m1
            // select below is bit-exact vs the reference m1/m2/cnt form.
            float minA = fmin3(fabsf(t[0]), fabsf(t[1]), fabsf(t[2]));
            float medA = fmed3(fabsf(t[0]), fabsf(t[1]), fabsf(t[2]));
            float minB = fmin3(fabsf(t[3]), fabsf(t[4]), fabsf(t[5]));
            float medB = fmed3(fabsf(t[3]), fabsf(t[4]), fabsf(t[5]));
            float m1 = fminf(minA, minB);
            float m2 = fmin3(fmaxf(minA, minB), medA, medB);
            // Only two possible output magnitudes per CN -> precompute both:
            float M1p = clamp0c(fmaf(m1, cnwa[it], nbias[it]));
            float M2p = clamp0c(fmaf(m2, cnwa[it], nbias[it]));
#pragma unroll
            for (int j = 0; j < 6; ++j) {
                float ext = (fabsf(t[j]) == m1) ? M2p : M1p;  // extrinsic mag
                unsigned sx = par ^ __float_as_uint(t[j]);    // sign of others
                // v_bfi_b32: take bit31 from sx, rest from ext
                float val = __uint_as_float((sx & 0x80000000u)
                                            | __float_as_uint(ext));
                c2v_lds[cn * 6 + j][tid] = val;
                // marginal accumulation, order = ((c0 + c1) + c2) as reference
                sum[j] = (cn == 0) ? val : (sum[j] + val);
            }
        }

        // decision + loss (order matches reference scatter)
#pragma unroll
        for (int i = 0; i < 6; ++i) {
            float dec = llr[i] + sum[i];
            // softplus(-dec) = max(-dec,0) + log(1+exp(-|dec|));
            // the log terms are accumulated as a product, one log at the end.
            accMax  += fmaxf(-dec, 0.f);
            prodLog *= 1.f + __expf(-fabsf(dec));
        }
    }

    // final dec (3 x 8B stores; wave writes 1536 contiguous bytes)
    float2* outd = (float2*)(out + 1 + b * N_ + 6 * k);
    outd[0] = make_float2(llr[0] + sum[0], llr[1] + sum[1]);
    outd[1] = make_float2(llr[2] + sum[2], llr[3] + sum[3]);
    outd[2] = make_float2(llr[4] + sum[4], llr[5] + sum[5]);

    // loss: wave64 shuffle -> LDS -> ONE PLAIN STORE per block (no atomics;
    // same-address RMWs previously pinned the kernel ~105us).
    float local_loss = accMax + __logf(prodLog);
#pragma unroll
    for (int off = 32; off > 0; off >>= 1)
        local_loss += __shfl_down(local_loss, off);
    const int lane = tid & 63;
    const int wid  = tid >> 6;
    if (lane == 0) wsum[wid] = local_loss;
    __syncthreads();
    if (tid == 0) {
        double t = ((double)wsum[0] + (double)wsum[1])
                 + ((double)wsum[2] + (double)wsum[3]);
        partials[blockIdx.x] = t;      // distinct address per block
    }
}

__global__ __launch_bounds__(256) void ldpc_finalize_kernel(
    const double* __restrict__ partials,  // [NBLOCKS_]
    float* __restrict__ out)
{
    double s = 0.0;
#pragma unroll
    for (int i = 0; i < NBLOCKS_ / 256; ++i)           // 8 loads/thread
        s += partials[threadIdx.x + 256 * i];
#pragma unroll
    for (int off = 32; off > 0; off >>= 1)
        s += __shfl_down(s, off);
    __shared__ double wsum[4];
    const int lane = threadIdx.x & 63;
    const int wid  = threadIdx.x >> 6;
    if (lane == 0) wsum[wid] = s;
    __syncthreads();
    if (threadIdx.x == 0) {
        double total = (wsum[0] + wsum[1]) + (wsum[2] + wsum[3]);
        out[0] = (float)(total * (1.0 / ((double)B_ * (double)N_)));
    }
}

extern "C" void kernel_launch(void* const* d_in, const int* in_sizes, int n_in,
                              void* d_out, int out_size, void* d_ws, size_t ws_size,
                              hipStream_t stream) {
    const float* llr_in    = (const float*)d_in[0];
    const float* cn_weight = (const float*)d_in[1];
    const float* ch_weight = (const float*)d_in[2];
    const float* cn_bias   = (const float*)d_in[3];
    // d_in[4]/d_in[5] (edge maps) unused: structure is closed-form (e%N, e/6).

    float*  out      = (float*)d_out;
    double* partials = (double*)d_ws;     // 2048 doubles = 16 KB, all overwritten

    ldpc_fused_kernel<<<NBLOCKS_, 256, 0, stream>>>(
        llr_in, cn_weight, ch_weight, cn_bias, out, partials);
    ldpc_finalize_kernel<<<1, 256, 0, stream>>>(partials, out);
}

// Round 3
// 90.826 us; speedup vs baseline: 1.1554x; 1.1300x over previous
//
#include <hip/hip_runtime.h>
#include <math.h>

// Regular (3,6) QC-LDPC, rate 1/2 (constants from reference).
#define B_      128
#define N_      24576
#define NPAIR_  2048     // component PAIRS: thread owns components 2p and 2p+1
#define ITERS_  10
#define CLIP_   20.0f
#define NBLOCKS_ ((B_ * NPAIR_) / 256)   // 1024 WGs -> 4/CU -> ONE generation

// Structure proof: edge_to_cn = e/6, edge_to_vn = e%N. CN c owns edges [6c,6c+6).
// For c = k, k+4096, k+8192 those edges map to VNs {6k..6k+5} exactly.
// => component k: CNs {k, k+4096, k+8192}, VNs {6k..6k+5}, 18 edges; fully
// independent -> whole decode fits in one thread's registers.
//
// R3: retry of the 2-comp/thread structure WITHOUT round-1's confounds:
//  - FULL unroll (round 0's proven form): weight arrays statically indexed ->
//    pure SGPR constants, no per-lap loads on the critical path.
//  - (256,4): 128-VGPR cap; persistent state 64 + ~30 transients ~= 100, fits.
//  - grid 1024 = 4 WG/CU resident = exactly one generation (round 0's (256,6)
//    ran a 6-then-2 convoy: ~2x a generation's wall time).
//  - 2 independent decode chains per lane -> 2x ILP to fill dep-stall slots.

__device__ __forceinline__ float fmed3(float a, float b, float c) {
    return __builtin_amdgcn_fmed3f(a, b, c);   // v_med3_f32
}
__device__ __forceinline__ float clipf(float x)   { return fmed3(x, -CLIP_, CLIP_); }
__device__ __forceinline__ float clamp0c(float x) { return fmed3(x, 0.0f, CLIP_); }
__device__ __forceinline__ float fmin3(float a, float b, float c) {
    return fminf(fminf(a, b), c);              // v_min3_f32
}
// Force a wave-uniform value into an SGPR.
__device__ __forceinline__ float rfl(float x) {
    return __uint_as_float(__builtin_amdgcn_readfirstlane(__float_as_uint(x)));
}

__global__ __launch_bounds__(256, 4) void ldpc_fused_kernel(
    const float* __restrict__ llr_in,     // [B, N]
    const float* __restrict__ cn_weight,  // [ITERS]
    const float* __restrict__ ch_weight,  // [ITERS]
    const float* __restrict__ cn_bias,    // [ITERS]
    float* __restrict__ out,              // [0]=loss (finalize), [1..]=dec [B,N]
    double* __restrict__ partials)        // d_ws: one slot per block, no atomics
{
    const int tid = threadIdx.x;
    const int gid = blockIdx.x * 256 + tid;
    const int b = gid >> 11;              // / NPAIR_
    const int p = gid & (NPAIR_ - 1);

    // Per-iteration weights -> SGPRs (statically indexed under the full
    // unroll, so these arrays never touch memory or VGPRs).
    float cwv[ITERS_], cnwa[ITERS_], nbias[ITERS_];
    unsigned cnws[ITERS_];
#pragma unroll
    for (int i = 0; i < ITERS_; ++i) {
        float w  = rfl(cn_weight[i]);
        cwv[i]   = rfl(ch_weight[i]);
        cnwa[i]  = fabsf(w);
        cnws[i]  = __float_as_uint(w) & 0x80000000u;
        nbias[i] = -rfl(cn_bias[i]);
    }

    // 12 contiguous channel LLRs (16B-aligned: byte offset = 48p + 98304b)
    const float4* p4 = (const float4*)(llr_in + b * N_ + 12 * p);
    float4 q0 = p4[0], q1 = p4[1], q2 = p4[2];
    float llr[2][6] = {
        { q0.x, q0.y, q0.z, q0.w, q1.x, q1.y },
        { q1.z, q1.w, q2.x, q2.y, q2.z, q2.w }
    };

    float c2v[2][3][6];
    float sum[2][6];
#pragma unroll
    for (int g = 0; g < 2; ++g)
#pragma unroll
        for (int i = 0; i < 6; ++i) {
            sum[g][i] = 0.f;
            c2v[g][0][i] = 0.f; c2v[g][1][i] = 0.f; c2v[g][2][i] = 0.f;
        }

    // Per-component loss accumulators (verified numerics: R1 passed absmax=0
    // with this exact split; 2 independent chains).
    float accMax[2]  = { 0.f, 0.f };
    float prodLog[2] = { 1.f, 1.f };   // 60 terms in (1,2] each -> <= 2^60, safe

#pragma unroll
    for (int it = 0; it < ITERS_; ++it) {
#pragma unroll
        for (int g = 0; g < 2; ++g) {
            // VN totals (shared by the 3 CNs of this component)
            float u6[6];
#pragma unroll
            for (int i = 0; i < 6; ++i) u6[i] = fmaf(llr[g][i], cwv[it], sum[g][i]);

#pragma unroll
            for (int cn = 0; cn < 3; ++cn) {
                // v2c = clip(u - c2v); sign bits tracked via float bitcasts
                float t[6];
                unsigned par = cnws[it];    // fold cn_weight sign into parity
#pragma unroll
                for (int j = 0; j < 6; ++j) {
                    t[j] = clipf(u6[j] - c2v[g][cn][j]);
                    par ^= __float_as_uint(t[j]);   // only bit31 meaningful
                }
                // Two-min via sorted-triple merge (abs as VOP3 modifiers).
                // Exact incl. ties: dup-min => m2 == m1 -> the (a==m1)?m2:m1
                // select below is bit-exact vs the reference m1/m2/cnt form.
                float minA = fmin3(fabsf(t[0]), fabsf(t[1]), fabsf(t[2]));
                float medA = fmed3(fabsf(t[0]), fabsf(t[1]), fabsf(t[2]));
                float minB = fmin3(fabsf(t[3]), fabsf(t[4]), fabsf(t[5]));
                float medB = fmed3(fabsf(t[3]), fabsf(t[4]), fabsf(t[5]));
                float m1 = fminf(minA, minB);
                float m2 = fmin3(fmaxf(minA, minB), medA, medB);
                // Only two possible output magnitudes per CN:
                float M1p = clamp0c(fmaf(m1, cnwa[it], nbias[it]));
                float M2p = clamp0c(fmaf(m2, cnwa[it], nbias[it]));
#pragma unroll
                for (int j = 0; j < 6; ++j) {
                    float ext = (fabsf(t[j]) == m1) ? M2p : M1p;
                    unsigned sx = par ^ __float_as_uint(t[j]); // sign of others
                    // v_bfi_b32: bit31 from sx, rest from ext
                    c2v[g][cn][j] = __uint_as_float((sx & 0x80000000u)
                                                    | __float_as_uint(ext));
                }
            }

            // marginals + loss (add order per component matches reference)
#pragma unroll
            for (int i = 0; i < 6; ++i) {
                sum[g][i] = (c2v[g][0][i] + c2v[g][1][i]) + c2v[g][2][i];
                float dec = llr[g][i] + sum[g][i];
                // softplus(-dec) = max(-dec,0) + log(1+exp(-|dec|));
                // log terms accumulated as a product, ONE log per component.
                accMax[g]  += fmaxf(-dec, 0.f);
                prodLog[g] *= 1.f + __expf(-fabsf(dec));
            }
        }
    }

    // final dec: 12 contiguous floats -> 3 x dwordx4
    float d[12];
#pragma unroll
    for (int g = 0; g < 2; ++g)
#pragma unroll
        for (int i = 0; i < 6; ++i) d[6 * g + i] = llr[g][i] + sum[g][i];

    float4* outd = (float4*)(out + 1 + b * N_ + 12 * p);
    outd[0] = make_float4(d[0], d[1], d[2],  d[3]);
    outd[1] = make_float4(d[4], d[5], d[6],  d[7]);
    outd[2] = make_float4(d[8], d[9], d[10], d[11]);

    // loss: wave64 shuffle -> LDS -> ONE PLAIN STORE per block (no atomics).
    float local_loss = (accMax[0] + __logf(prodLog[0]))
                     + (accMax[1] + __logf(prodLog[1]));
#pragma unroll
    for (int off = 32; off > 0; off >>= 1)
        local_loss += __shfl_down(local_loss, off);
    __shared__ float wsum[4];
    const int lane = tid & 63;
    const int wid  = tid >> 6;
    if (lane == 0) wsum[wid] = local_loss;
    __syncthreads();
    if (tid == 0) {
        double t = ((double)wsum[0] + (double)wsum[1])
                 + ((double)wsum[2] + (double)wsum[3]);
        partials[blockIdx.x] = t;      // distinct address per block
    }
}

__global__ __launch_bounds__(256) void ldpc_finalize_kernel(
    const double* __restrict__ partials,  // [NBLOCKS_]
    float* __restrict__ out)
{
    double s = 0.0;
#pragma unroll
    for (int i = 0; i < NBLOCKS_ / 256; ++i)           // 4 loads/thread
        s += partials[threadIdx.x + 256 * i];
#pragma unroll
    for (int off = 32; off > 0; off >>= 1)
        s += __shfl_down(s, off);
    __shared__ double wsum[4];
    const int lane = threadIdx.x & 63;
    const int wid  = threadIdx.x >> 6;
    if (lane == 0) wsum[wid] = s;
    __syncthreads();
    if (threadIdx.x == 0) {
        double total = (wsum[0] + wsum[1]) + (wsum[2] + wsum[3]);
        out[0] = (float)(total * (1.0 / ((double)B_ * (double)N_)));
    }
}

extern "C" void kernel_launch(void* const* d_in, const int* in_sizes, int n_in,
                              void* d_out, int out_size, void* d_ws, size_t ws_size,
                              hipStream_t stream) {
    const float* llr_in    = (const float*)d_in[0];
    const float* cn_weight = (const float*)d_in[1];
    const float* ch_weight = (const float*)d_in[2];
    const float* cn_bias   = (const float*)d_in[3];
    // d_in[4]/d_in[5] (edge maps) unused: structure is closed-form (e%N, e/6).

    float*  out      = (float*)d_out;
    double* partials = (double*)d_ws;     // 1024 doubles = 8 KB, all overwritten

    ldpc_fused_kernel<<<NBLOCKS_, 256, 0, stream>>>(
        llr_in, cn_weight, ch_weight, cn_bias, out, partials);
    ldpc_finalize_kernel<<<1, 256, 0, stream>>>(partials, out);
}